// Round 1
// baseline (109.449 us; speedup 1.0000x reference)
//
#include <hip/hip_runtime.h>

// DupireNeuralModel local-vol Monte Carlo scan.
// dW: [N_T, M] f32 (pre-scaled by sqrt(dt)); out: [N_T, M] f32 path matrix.
// Row 0 = S0; row t+1 = step(row t, dW[t]) for t in [0, N_T-2].

#define MC_M 262144
#define MC_NT 256
#define PATHS_PER_THREAD 4
#define BLOCK 256

__device__ __forceinline__ float mc_step(float S, float dw, float tc) {
    // y = sqrt(S/S0 + 0.1) * (t + 0.1);  sigma = 0.3 + y*exp(-y)
    float y   = sqrtf(fmaf(S, 0.01f, 0.1f)) * tc;
    float sig = fmaf(y, __expf(-y), 0.3f);
    // S + r*S*dt + sigma*S*dw   (r*dt = 0.05*0.004 = 2e-4)
    return fmaf(sig * S, dw, fmaf(2.0e-4f, S, S));
}

__global__ __launch_bounds__(BLOCK) void dupire_mc_kernel(
    const float* __restrict__ dW, float* __restrict__ out)
{
    const int base = (blockIdx.x * BLOCK + threadIdx.x) * PATHS_PER_THREAD;
    const float T_STEP = 1.024f / 255.0f;  // jnp.linspace(0, N_T*dt, N_T) step

    float4 S;
    S.x = S.y = S.z = S.w = 100.0f;
    *reinterpret_cast<float4*>(out + base) = S;  // row 0 = S0

    const float* dwp = dW + base;

    // Depth-2 prefetch pipeline. dW has N_T=256 rows, we consume rows 0..254;
    // prefetching row t+2 (max 255) is always in-bounds.
    float4 dwA = *reinterpret_cast<const float4*>(dwp);
    float4 dwB = *reinterpret_cast<const float4*>(dwp + (size_t)MC_M);

    #pragma unroll 2
    for (int t = 0; t < MC_NT - 2; ++t) {
        float4 dw = dwA;
        dwA = dwB;
        dwB = *reinterpret_cast<const float4*>(dwp + (size_t)(t + 2) * MC_M);

        const float tc = fmaf((float)t, T_STEP, 0.1f);
        S.x = mc_step(S.x, dw.x, tc);
        S.y = mc_step(S.y, dw.y, tc);
        S.z = mc_step(S.z, dw.z, tc);
        S.w = mc_step(S.w, dw.w, tc);

        *reinterpret_cast<float4*>(out + (size_t)(t + 1) * MC_M + base) = S;
    }

    // Final step: t = N_T-2 = 254, consumes dwA (row 254), writes row 255.
    {
        const int t = MC_NT - 2;
        const float tc = fmaf((float)t, T_STEP, 0.1f);
        S.x = mc_step(S.x, dwA.x, tc);
        S.y = mc_step(S.y, dwA.y, tc);
        S.z = mc_step(S.z, dwA.z, tc);
        S.w = mc_step(S.w, dwA.w, tc);
        *reinterpret_cast<float4*>(out + (size_t)(t + 1) * MC_M + base) = S;
    }
}

extern "C" void kernel_launch(void* const* d_in, const int* in_sizes, int n_in,
                              void* d_out, int out_size, void* d_ws, size_t ws_size,
                              hipStream_t stream) {
    const float* dW = (const float*)d_in[0];
    float* out = (float*)d_out;

    const int total_threads = MC_M / PATHS_PER_THREAD;       // 65536
    const int grid = total_threads / BLOCK;                  // 256 blocks
    dupire_mc_kernel<<<grid, BLOCK, 0, stream>>>(dW, out);
}

// Round 3
// 93.910 us; speedup vs baseline: 1.1655x; 1.1655x over previous
//
#include <hip/hip_runtime.h>

// DupireNeuralModel local-vol Monte Carlo scan.
// dW: [N_T, M] f32 (pre-scaled by sqrt(dt)); out: [N_T, M] f32 path matrix.
// Row 0 = S0; row t+1 = step(row t, dW[t]) for t in [0, N_T-2].
//
// Memory-bound streaming kernel: 268 MB read + 268 MB write, floor ~85 us
// at 6.3 TB/s. Design: 2 paths/thread (8B/lane), 512 blocks x 256
// = 8 waves/CU for TLP, plus a depth-8 prefetch ring (32 KB outstanding
// reads/CU) so HBM latency is covered even at this modest occupancy.
// Non-temporal loads/stores: both streams are touch-once, 512 MB > L3.

#define MC_M 262144
#define MC_NT 256
#define PPT 2
#define BLOCK 256
#define DEPTH 8   // prefetch ring depth

typedef float f32x2 __attribute__((ext_vector_type(2)));  // native vector type:
// __builtin_nontemporal_* accepts these (HIP_vector_type float2 is a struct -> rejected)

__device__ __forceinline__ float mc_step(float S, float dw, float tc) {
    // y = sqrt(S/S0 + 0.1) * (t + 0.1);  sigma = 0.3 + y*exp(-y)
    float y   = sqrtf(fmaf(S, 0.01f, 0.1f)) * tc;
    float sig = fmaf(y, __expf(-y), 0.3f);
    // S + r*S*dt + sigma*S*dw   (r*dt = 2e-4)
    return fmaf(sig * S, dw, fmaf(2.0e-4f, S, S));
}

__global__ __launch_bounds__(BLOCK) void dupire_mc_kernel(
    const float* __restrict__ dW, float* __restrict__ out)
{
    const int base = (blockIdx.x * BLOCK + threadIdx.x) * PPT;
    const float T_STEP = 1.024f / 255.0f;  // jnp.linspace(0, N_T*dt, N_T) step

    const size_t stride2 = MC_M / 2;  // row stride in f32x2 units
    const f32x2* dwp = reinterpret_cast<const f32x2*>(dW) + base / 2;
    f32x2*       op  = reinterpret_cast<f32x2*>(out) + base / 2;

    f32x2 S; S.x = S.y = 100.0f;
    __builtin_nontemporal_store(S, op);  // row 0 = S0

    // Prologue: fill the ring with dW rows 0..7.
    f32x2 buf[DEPTH];
    #pragma unroll
    for (int i = 0; i < DEPTH; ++i)
        buf[i] = __builtin_nontemporal_load(dwp + (size_t)i * stride2);

    // Main loop: t = 0..247 (31*8 iterations, inner fully unrolled so
    // ring indices are compile-time constants -> stays in registers).
    // Consumes dW row t, prefetches row t+8 (max 255, always in-bounds).
    for (int k = 0; k < (MC_NT - DEPTH) / DEPTH; ++k) {
        const int tb = k * DEPTH;
        #pragma unroll
        for (int j = 0; j < DEPTH; ++j) {
            const int t = tb + j;
            const f32x2 dw = buf[j];
            buf[j] = __builtin_nontemporal_load(dwp + (size_t)(t + DEPTH) * stride2);
            const float tc = fmaf((float)t, T_STEP, 0.1f);
            S.x = mc_step(S.x, dw.x, tc);
            S.y = mc_step(S.y, dw.y, tc);
            __builtin_nontemporal_store(S, op + (size_t)(t + 1) * stride2);
        }
    }

    // Tail: t = 248..254 (7 iterations, static ring indices).
    #pragma unroll
    for (int j = 0; j < DEPTH - 1; ++j) {
        const int t = (MC_NT - DEPTH) + j;
        const f32x2 dw = buf[j];
        const float tc = fmaf((float)t, T_STEP, 0.1f);
        S.x = mc_step(S.x, dw.x, tc);
        S.y = mc_step(S.y, dw.y, tc);
        __builtin_nontemporal_store(S, op + (size_t)(t + 1) * stride2);
    }
}

extern "C" void kernel_launch(void* const* d_in, const int* in_sizes, int n_in,
                              void* d_out, int out_size, void* d_ws, size_t ws_size,
                              hipStream_t stream) {
    const float* dW = (const float*)d_in[0];
    float* out = (float*)d_out;

    const int total_threads = MC_M / PPT;        // 131072
    const int grid = total_threads / BLOCK;      // 512 blocks -> 8 waves/CU
    dupire_mc_kernel<<<grid, BLOCK, 0, stream>>>(dW, out);
}